// Round 2
// 173.329 us; speedup vs baseline: 1.0817x; 1.0817x over previous
//
#include <hip/hip_runtime.h>
#include <hip/hip_bf16.h>

typedef _Float16 f16x8 __attribute__((ext_vector_type(8)));
typedef _Float16 f16x4 __attribute__((ext_vector_type(4)));
typedef __fp16 fp16x2 __attribute__((ext_vector_type(2)));
typedef float f32x4 __attribute__((ext_vector_type(4)));

#define BATCH 4
#define SEQ 4096
#define EMB 1024
#define HEAD 64

// Async global->LDS, 16B per lane. LDS dest is WAVE-UNIFORM base; HW adds
// lane*16. Global src is per-lane (we make it base + lane*16 = coalesced).
__device__ __forceinline__ void async_copy16(const void* gsrc, void* ldst) {
  __builtin_amdgcn_global_load_lds(
      (const __attribute__((address_space(1))) void*)gsrc,
      (__attribute__((address_space(3))) void*)ldst,
      16, 0, 0);
}

// ---------------------------------------------------------------------------
// Kernel 1: weights -> glds-tiled WT (unchanged).
// ---------------------------------------------------------------------------
__global__ __launch_bounds__(256) void wtrans_kernel(
    const float* __restrict__ Wk, const float* __restrict__ Wq,
    const float* __restrict__ Wv, _Float16* __restrict__ WT) {
  int id = blockIdx.x * 256 + threadIdx.x;   // 0 .. 24575 (unit index)
  int step = id / 1536;
  int rem = id - step * 1536;
  int G = rem / 192;
  int n = rem - G * 192;
  int sel = n >> 6;
  int col = n & 63;
  const float* src = (sel == 0) ? Wq : (sel == 1) ? Wk : Wv;
  const float scale = (sel == 0) ? 0.03125f : 1.0f;
  f16x8 u;
#pragma unroll
  for (int j = 0; j < 8; ++j) {
    int k = step * 64 + G * 8 + j;
    u[j] = (_Float16)(src[k * 64 + col] * scale);
  }
  *(f16x8*)(WT + (size_t)id * 8) = u;
}

// ---------------------------------------------------------------------------
// Kernel 2: QKV projection (unchanged).
// ---------------------------------------------------------------------------
__global__ __launch_bounds__(256) void proj_kernel(
    const float* __restrict__ x, const _Float16* __restrict__ WT,
    _Float16* __restrict__ Qh, _Float16* __restrict__ KT,
    _Float16* __restrict__ VT) {
  __shared__ _Float16 wtl[2][12288];   // 2 x 24 KB, unit u = G*192 + n
  const int tid = threadIdx.x;
  const int wave = tid >> 6;
  const int lane = tid & 63;
  const int quad = lane >> 4;
  const int l16 = lane & 15;
  const int wm = wave & 1;
  const int wn = wave >> 1;
  const int rowblk = blockIdx.x * 32;

  const float* xr = x + (size_t)(rowblk + wm * 16 + l16) * EMB + quad * 8;

  f32x4 acc[6];
#pragma unroll
  for (int t = 0; t < 6; ++t) acc[t] = (f32x4){0.f, 0.f, 0.f, 0.f};

#pragma unroll
  for (int i = 0; i < 6; ++i) {
    const int c = wave * 6 + i;
    async_copy16(WT + (size_t)c * 512 + lane * 8, (char*)&wtl[0][0] + c * 1024);
  }
  float4 xa = *(const float4*)(xr);
  float4 xb = *(const float4*)(xr + 4);
  float4 xc = *(const float4*)(xr + 32);
  float4 xd = *(const float4*)(xr + 36);
  __syncthreads();

  int p = 0;
  for (int step = 0; step < 16; ++step) {
    if (step < 15) {
      const _Float16* wsrc = WT + (size_t)(step + 1) * 12288;
#pragma unroll
      for (int i = 0; i < 6; ++i) {
        const int c = wave * 6 + i;
        async_copy16(wsrc + (size_t)c * 512 + lane * 8,
                     (char*)&wtl[p ^ 1][0] + c * 1024);
      }
    }
    fp16x2 p0 = __builtin_amdgcn_cvt_pkrtz(xa.x, xa.y);
    fp16x2 p1 = __builtin_amdgcn_cvt_pkrtz(xa.z, xa.w);
    fp16x2 p2 = __builtin_amdgcn_cvt_pkrtz(xb.x, xb.y);
    fp16x2 p3 = __builtin_amdgcn_cvt_pkrtz(xb.z, xb.w);
    f16x8 af0, af1;
    af0[0] = (_Float16)p0[0]; af0[1] = (_Float16)p0[1];
    af0[2] = (_Float16)p1[0]; af0[3] = (_Float16)p1[1];
    af0[4] = (_Float16)p2[0]; af0[5] = (_Float16)p2[1];
    af0[6] = (_Float16)p3[0]; af0[7] = (_Float16)p3[1];
    p0 = __builtin_amdgcn_cvt_pkrtz(xc.x, xc.y);
    p1 = __builtin_amdgcn_cvt_pkrtz(xc.z, xc.w);
    p2 = __builtin_amdgcn_cvt_pkrtz(xd.x, xd.y);
    p3 = __builtin_amdgcn_cvt_pkrtz(xd.z, xd.w);
    af1[0] = (_Float16)p0[0]; af1[1] = (_Float16)p0[1];
    af1[2] = (_Float16)p1[0]; af1[3] = (_Float16)p1[1];
    af1[4] = (_Float16)p2[0]; af1[5] = (_Float16)p2[1];
    af1[6] = (_Float16)p3[0]; af1[7] = (_Float16)p3[1];
    if (step < 15) {
      const float* xn = xr + (step + 1) * 64;
      xa = *(const float4*)(xn);
      xb = *(const float4*)(xn + 4);
      xc = *(const float4*)(xn + 32);
      xd = *(const float4*)(xn + 36);
    }
#pragma unroll
    for (int t = 0; t < 6; ++t) {
      const int n = wn * 96 + t * 16 + l16;
      const f16x8 b0 = *(const f16x8*)&wtl[p][(size_t)((0 * 4 + quad) * 192 + n) * 8];
      const f16x8 b1 = *(const f16x8*)&wtl[p][(size_t)((1 * 4 + quad) * 192 + n) * 8];
      acc[t] = __builtin_amdgcn_mfma_f32_16x16x32_f16(af0, b0, acc[t], 0, 0, 0);
      acc[t] = __builtin_amdgcn_mfma_f32_16x16x32_f16(af1, b1, acc[t], 0, 0, 0);
    }
    __syncthreads();
    p ^= 1;
  }

  const int rowbase = rowblk + wm * 16;
  const int b = rowbase >> 12;
  const int trbase = (rowbase & 4095) + quad * 4;
#pragma unroll
  for (int t = 0; t < 6; ++t) {
    const int g = wn * 6 + t;
    if (g < 4) {                         // Q row-major (scaled via Wq)
      const int h = g * 16 + l16;
#pragma unroll
      for (int r = 0; r < 4; ++r)
        Qh[(size_t)(rowbase + quad * 4 + r) * HEAD + h] = (_Float16)acc[t][r];
    } else if (g < 8) {                  // K -> KT[b][kt][G=h/8][key][h%8]
      const int h = (g - 4) * 16 + l16;
#pragma unroll
      for (int r = 0; r < 4; ++r) {
        const int t0 = trbase + r;
        const size_t ad = ((size_t)((b * 64 + (t0 >> 6)) * 8 + (h >> 3)) * 64 +
                           (t0 & 63)) * 8 + (h & 7);
        KT[ad] = (_Float16)acc[t][r];
      }
    } else {                             // V -> VT[b][kt][Gk=keygrp][h][key%8]
      const int h = (g - 8) * 16 + l16;
      f16x4 pk;
      pk[0] = (_Float16)acc[t][0]; pk[1] = (_Float16)acc[t][1];
      pk[2] = (_Float16)acc[t][2]; pk[3] = (_Float16)acc[t][3];
      const size_t ad = ((size_t)((b * 64 + (trbase >> 6)) * 8 + ((trbase & 63) >> 3)) * 512) +
                        (size_t)h * 8 + (trbase & 7);
      *(f16x4*)(VT + ad) = pk;
    }
  }
}

// ---------------------------------------------------------------------------
// Kernel 3: causal flash attention, restructured for occupancy.
// q-tile = 16 rows (256 tiles/batch, nkt(j) = j/4+1); pairs (j, 255-j) give
// uniform ~65 steps/block; grid 512 -> 2 co-resident blocks/CU (8 waves/CU,
// LDS ~34.5 KB/block). Wave split per 64-key step:
//   QK: wave w owns 16-key slice (2 MFMA k=32) -> P written to BLOCK-SHARED
//       pl[16][72] (16B-aligned rows, bank-uniform).
//   PV: wave w owns 16-wide h-slice with full k=64 (2 MFMA) -> single f32x4
//       accumulator, NO O-combine buffer; only a 256B row-sum combine.
// 2 barriers/step (P crosses waves) — hidden by the co-resident block.
// ---------------------------------------------------------------------------
__global__ __launch_bounds__(256) void flash_kernel(
    const _Float16* __restrict__ Qh, const _Float16* __restrict__ KT,
    const _Float16* __restrict__ VT, float* __restrict__ out) {
  __shared__ _Float16 kv[2][8192];   // 16 KB/buf: K units 0..511, V 512..1023
  __shared__ _Float16 pl[16][72];    // shared P tile, row stride 144 B
  __shared__ float lds_l[4][16];     // per-wave row sums
  const int tid = threadIdx.x;
  const int w = tid >> 6;            // wave = key-slice (QK) / h-slice (PV)
  const int lane = tid & 63;
  const int quad = lane >> 4;
  const int l16 = lane & 15;
  const int b = blockIdx.x & 3;      // XCD = blockIdx%8 -> one batch per XCD
  const int pairi = blockIdx.x >> 2; // 0..127

  const _Float16* Q = Qh + (size_t)b * SEQ * HEAD;
  const f32x4 zero = {0.f, 0.f, 0.f, 0.f};

  for (int half = 0; half < 2; ++half) {
    const int j = half ? pairi : (255 - pairi);  // heavy tile first
    const int qb = j * 16;
    const int nkt = (j >> 2) + 1;

    // Q A-frags: rows qb+l16 (all 4 waves load same 16 rows; L1-cached)
    const f16x8 aq0 = *(const f16x8*)(Q + (size_t)(qb + l16) * HEAD + quad * 8);
    const f16x8 aq1 = *(const f16x8*)(Q + (size_t)(qb + l16) * HEAD + 32 + quad * 8);
    const int qrow = qb + quad * 4;  // +r

    f32x4 oc = zero;                 // wave's h-slice accumulator
    float lacc[4] = {0.f, 0.f, 0.f, 0.f};

    // stage tile 0 into buf 0: 16 chunks (8 K + 8 V), 4 per wave
    {
      const size_t tb = (size_t)(b * 64 + 0) * 8;
#pragma unroll
      for (int i = 0; i < 4; ++i) {
        const int c = w * 4 + i;
        const _Float16* src = (c < 8) ? (KT + (tb + c) * 512 + lane * 8)
                                      : (VT + (tb + (c - 8)) * 512 + lane * 8);
        async_copy16(src, (char*)&kv[0][0] + c * 1024);
      }
    }
    __syncthreads();

    int p = 0;
    for (int kt = 0; kt < nkt; ++kt) {
      if (kt + 1 < nkt) {            // stage next tile (overlaps compute)
        const size_t tb = (size_t)(b * 64 + kt + 1) * 8;
#pragma unroll
        for (int i = 0; i < 4; ++i) {
          const int c = w * 4 + i;
          const _Float16* src = (c < 8) ? (KT + (tb + c) * 512 + lane * 8)
                                        : (VT + (tb + (c - 8)) * 512 + lane * 8);
          async_copy16(src, (char*)&kv[p ^ 1][0] + c * 1024);
        }
      }
      // QK: wave's 16-key slice of the 64-key tile
      const f16x8 kb0 = *(const f16x8*)&kv[p][(size_t)((0 + quad) * 64 + w * 16 + l16) * 8];
      const f16x8 kb1 = *(const f16x8*)&kv[p][(size_t)((4 + quad) * 64 + w * 16 + l16) * 8];
      f32x4 s = __builtin_amdgcn_mfma_f32_16x16x32_f16(aq0, kb0, zero, 0, 0, 0);
      s = __builtin_amdgcn_mfma_f32_16x16x32_f16(aq1, kb1, s, 0, 0, 0);

      const int kcol = kt * 64 + w * 16 + l16;
      float pv[4];
      if (kt == nkt - 1) {           // diagonal tile: mask then exp
#pragma unroll
        for (int r = 0; r < 4; ++r)
          pv[r] = (kcol > qrow + r) ? 0.f : __expf(s[r]);
      } else {
#pragma unroll
        for (int r = 0; r < 4; ++r) pv[r] = __expf(s[r]);
      }
#pragma unroll
      for (int r = 0; r < 4; ++r) {
        lacc[r] += pv[r];
        pl[quad * 4 + r][w * 16 + l16] = (_Float16)pv[r];
      }
      __syncthreads();               // P visible to all waves

      // PV: wave's 16-wide h-slice, full k=64
      const f16x8 ap0 = *(const f16x8*)&pl[l16][quad * 8];
      const f16x8 ap1 = *(const f16x8*)&pl[l16][32 + quad * 8];
      const f16x8 bv0 = *(const f16x8*)&kv[p][4096 + (size_t)((0 + quad) * 64 + w * 16 + l16) * 8];
      const f16x8 bv1 = *(const f16x8*)&kv[p][4096 + (size_t)((4 + quad) * 64 + w * 16 + l16) * 8];
      oc = __builtin_amdgcn_mfma_f32_16x16x32_f16(ap0, bv0, oc, 0, 0, 0);
      oc = __builtin_amdgcn_mfma_f32_16x16x32_f16(ap1, bv1, oc, 0, 0, 0);
      __syncthreads();               // P + kv[p] consumed
      p ^= 1;
    }

    // row-sum combine (4 waves x 16-key slices) then normalize + write
#pragma unroll
    for (int r = 0; r < 4; ++r) {
      float l = lacc[r];
      l += __shfl_xor(l, 1);
      l += __shfl_xor(l, 2);
      l += __shfl_xor(l, 4);
      l += __shfl_xor(l, 8);
      if (l16 == 0) lds_l[w][quad * 4 + r] = l;
    }
    __syncthreads();
#pragma unroll
    for (int r = 0; r < 4; ++r) {
      const float lsum = lds_l[0][quad * 4 + r] + lds_l[1][quad * 4 + r] +
                         lds_l[2][quad * 4 + r] + lds_l[3][quad * 4 + r];
      out[((size_t)b * SEQ + qb + quad * 4 + r) * HEAD + w * 16 + l16] =
          oc[r] * (1.0f / lsum);
    }
    __syncthreads();                 // LDS reused by the pair's second tile
  }
}

extern "C" void kernel_launch(void* const* d_in, const int* in_sizes, int n_in,
                              void* d_out, int out_size, void* d_ws, size_t ws_size,
                              hipStream_t stream) {
  const float* x  = (const float*)d_in[0];
  const float* Wk = (const float*)d_in[1];
  const float* Wq = (const float*)d_in[2];
  const float* Wv = (const float*)d_in[3];
  float* out = (float*)d_out;

  // ws layout: Qh[0,2MB) KT[2MB,4MB) VT[4MB,6MB) WT[6MB,6.375MB)
  char* ws = (char*)d_ws;
  _Float16* Qh = (_Float16*)(ws);
  _Float16* KT = (_Float16*)(ws + (size_t)2 * 1024 * 1024);
  _Float16* VT = (_Float16*)(ws + (size_t)4 * 1024 * 1024);
  _Float16* WT = (_Float16*)(ws + (size_t)6 * 1024 * 1024);

  wtrans_kernel<<<96, 256, 0, stream>>>(Wk, Wq, Wv, WT);
  proj_kernel<<<512, 256, 0, stream>>>(x, WT, Qh, KT, VT);
  flash_kernel<<<512, 256, 0, stream>>>(Qh, KT, VT, out);
}